// Round 1
// baseline (100.821 us; speedup 1.0000x reference)
//
#include <hip/hip_runtime.h>

#define B_SZ 4096
#define D_SZ 1024
#define NB 32
#define DF 16          // features per tile
#define RB 512         // rows per tile
#define NFT (D_SZ / DF)   // 64 feature tiles
#define LSQ_STRIDE 9   // shifted-edge quads: 9 float4 per feature
#define CO_STRIDE  33  // coef quads: 33 float4 per feature

constexpr float MBW = 0.001f;
constexpr float MBH = 0.001f;

// ---------------------------------------------------------------------------
// Fused spline kernel. Block = 512 thr (8 waves), tile = 16 feat x 512 rows,
// grid = 64 f-tiles x 8 r-tiles = 512 blocks (2/CU).
//
// Phase 1 (one pass, 8x total redundancy): 16 segments of 32 lanes each run
// the softmax/cumsum/monotone-derivative pipeline for one feature, writing
// coef quads (a,b,c=d_left,d=chl) and shifted edge quads into 10.8 KB LDS.
//
// Phase 2: lane owns 4 consecutive features (quad = lane>>4), row = lane&15;
// float4 I/O (full 64B lines per 4-lane cluster). Search: 7 register cmps
// (quad idx) -> 1 ds_read_b128 shifted quad -> 1 ds_read_b128 coef.
//
// CHANGE vs prev round: logabsdet partials go to ws[ft*B + row] as plain
// coalesced stores (unique writer per (ft,row)) instead of 262K device-scope
// atomicAdds (64 cross-XCD writers per lad address). A tiny second kernel
// reduces the 64 partials per row. Also removes the lad memset dispatch.
// ---------------------------------------------------------------------------
__global__ __launch_bounds__(512) void spline_fused(
    const float* __restrict__ uw, const float* __restrict__ uh,
    const float* __restrict__ udl, const float* __restrict__ udr,
    const float4* __restrict__ inp,
    float4* __restrict__ out, float* __restrict__ ws)
{
    __shared__ float4 sLsQ  [DF * LSQ_STRIDE];   // 2.3 KB
    __shared__ float4 sCoefQ[DF * CO_STRIDE];    // 8.45 KB

    const int tid = threadIdx.x;
    const int ft = blockIdx.x & 63;              // 64 feature tiles
    const int rt = blockIdx.x >> 6;              // 8 row tiles
    const int f0 = ft * DF;
    const int r0 = rt * RB;

    // ---------------- phase 1: params, one segment per feature ----------------
    {
        const int s = tid >> 5;        // feature within tile: 0..15
        const int k = tid & 31;        // bin
        const int f = f0 + s;

        const float w_raw = uw[f * NB + k];
        const float h_raw = uh[f * NB + k];

        float m = w_raw;
        for (int mm = 16; mm >= 1; mm >>= 1) m = fmaxf(m, __shfl_xor(m, mm));
        const float e = __expf(w_raw - m);
        float sum = e;
        for (int mm = 16; mm >= 1; mm >>= 1) sum += __shfl_xor(sum, mm);
        const float w = MBW + (1.0f - MBW * NB) * (e / sum);

        float mh = h_raw;
        for (int mm = 16; mm >= 1; mm >>= 1) mh = fmaxf(mh, __shfl_xor(mh, mm));
        const float eh = __expf(h_raw - mh);
        float sumh = eh;
        for (int mm = 16; mm >= 1; mm >>= 1) sumh += __shfl_xor(sumh, mm);
        const float h = MBH + (1.0f - MBH * NB) * (eh / sumh);

        const float slope = h / w;

        float cw = w, ch = h;
        for (int off = 1; off < 32; off <<= 1) {
            float t1 = __shfl_up(cw, off, 32);
            float t2 = __shfl_up(ch, off, 32);
            if (k >= off) { cw += t1; ch += t2; }
        }
        float chl = __shfl_up(ch, 1, 32); if (k == 0) chl = 0.0f;
        const float Ls = (k == 31) ? 2.0f : cw;   // sentinel > any x in [0,1)

        const float slope_n = __shfl_down(slope, 1, 32);
        const float w_n     = __shfl_down(w, 1, 32);
        const float min1 = fminf(fabsf(slope), fabsf(slope_n));
        const float min2 = 0.5f * (w_n * slope + w * slope_n) / (w + w_n);
        const float sg  = (slope   > 0.f ? 1.f : 0.f) - (slope   < 0.f ? 1.f : 0.f);
        const float sgn = (slope_n > 0.f ? 1.f : 0.f) - (slope_n < 0.f ? 1.f : 0.f);
        const float inner = fminf(min1, min2) * (sg + sgn);

        float d_right;
        if (k == 31) {
            const float x = udr[f];
            d_right = (1.0f / (1.0f + __expf(-x))) * 3.0f * slope;
        } else {
            d_right = inner;
        }
        const float inner_prev = __shfl_up(inner, 1, 32);
        float d_left;
        if (k == 0) {
            const float x = udl[f];
            d_left = (1.0f / (1.0f + __expf(-x))) * 3.0f * slope;
        } else {
            d_left = inner_prev;
        }

        const float a = (d_left + d_right - 2.0f * slope) / (w * w);
        const float b = (3.0f * slope - 2.0f * d_left - d_right) / w;

        sCoefQ[s * CO_STRIDE + k] = make_float4(a, b, d_left, chl);

        float q0 = __shfl(Ls, (4 * k - 1) & 31, 32);
        float q1 = __shfl(Ls, (4 * k    ) & 31, 32);
        float q2 = __shfl(Ls, (4 * k + 1) & 31, 32);
        float q3 = __shfl(Ls, (4 * k + 2) & 31, 32);
        if (k == 0) q0 = 0.0f;                    // L[-1]
        if (k < 8) sLsQ[s * LSQ_STRIDE + k] = make_float4(q0, q1, q2, q3);
    }
    __syncthreads();

    // ---------------- phase 2: evaluate ----------------
    const int lane   = tid & 63;
    const int waveId = tid >> 6;          // 0..7
    const int flq    = lane >> 4;         // feature quad: 0..3
    const int rl     = lane & 15;         // row within wave group
    const int flbase = flq * 4;

    // coarse quad boundaries -> registers: C[c] = L[4c+3] = quad(c+1).x
    float C0[7], C1[7], C2[7], C3[7];
    #pragma unroll
    for (int c = 0; c < 7; ++c) {
        C0[c] = sLsQ[(flbase + 0) * LSQ_STRIDE + c + 1].x;
        C1[c] = sLsQ[(flbase + 1) * LSQ_STRIDE + c + 1].x;
        C2[c] = sLsQ[(flbase + 2) * LSQ_STRIDE + c + 1].x;
        C3[c] = sLsQ[(flbase + 3) * LSQ_STRIDE + c + 1].x;
    }

    const int rbase = r0 + waveId * 16 + rl;          // +128 per iter
    const int base  = rbase * (D_SZ / 4) + ft * 4 + flq;
    const int iterStride = 128 * (D_SZ / 4);          // 128 rows per iter

    #pragma unroll
    for (int it = 0; it < RB / 128; ++it) {
        const float4 x4 = inp[base + it * iterStride];
        const float xv[4] = {x4.x, x4.y, x4.z, x4.w};

        float4 o4;
        float* ov = (float*)&o4;
        float prod = 1.0f;

        #pragma unroll
        for (int j = 0; j < 4; ++j) {
            const float x = xv[j];
            const float* Cp = (j == 0) ? C0 : (j == 1) ? C1 : (j == 2) ? C2 : C3;

            int o = 0;
            #pragma unroll
            for (int c = 0; c < 7; ++c) o += (x >= Cp[c]) ? 1 : 0;

            const float4 q = sLsQ[(flbase + j) * LSQ_STRIDE + o];
            const int cnt = (x >= q.y ? 1 : 0) + (x >= q.z ? 1 : 0)
                          + (x >= q.w ? 1 : 0);
            const float cwl = (cnt == 0) ? q.x
                            : (cnt == 1) ? q.y
                            : (cnt == 2) ? q.z : q.w;

            const float4 cf = sCoefQ[(flbase + j) * CO_STRIDE + 4 * o + cnt];
            const float s = x - cwl;
            float oo = ((cf.x * s + cf.y) * s + cf.z) * s + cf.w;
            ov[j] = fminf(fmaxf(oo, 0.0f), 1.0f);
            const float der = (3.0f * cf.x * s + 2.0f * cf.y) * s + cf.z;
            prod *= der;
        }

        out[base + it * iterStride] = o4;

        // sum across the 4 feature quads (xor classes share lane&15 == row)
        float lsum = __logf(fabsf(prod));
        lsum += __shfl_xor(lsum, 16);
        lsum += __shfl_xor(lsum, 32);
        // unique writer per (ft, row): plain coalesced store, no atomics
        if (lane < 16) ws[ft * B_SZ + rbase + it * 128] = lsum;
    }
}

// ---------------------------------------------------------------------------
// Reduce the 64 per-ftile partials per row into lad. 16 blocks x 256 thr;
// fully coalesced (256 consecutive rows per ft-slice read per block).
// ---------------------------------------------------------------------------
__global__ __launch_bounds__(256) void lad_reduce(
    const float* __restrict__ ws, float* __restrict__ lad)
{
    const int r = blockIdx.x * 256 + threadIdx.x;
    float s = 0.0f;
    #pragma unroll
    for (int ftile = 0; ftile < NFT; ++ftile)
        s += ws[ftile * B_SZ + r];
    lad[r] = s;
}

// ---------------------------------------------------------------------------
extern "C" void kernel_launch(void* const* d_in, const int* in_sizes, int n_in,
                              void* d_out, int out_size, void* d_ws, size_t ws_size,
                              hipStream_t stream)
{
    const float* inputs = (const float*)d_in[0];
    const float* uw     = (const float*)d_in[1];
    const float* uh     = (const float*)d_in[2];
    const float* udl    = (const float*)d_in[3];
    const float* udr    = (const float*)d_in[4];

    float* out = (float*)d_out;                 // B*D outputs
    float* lad = out + (size_t)B_SZ * D_SZ;     // B logabsdet sums
    float* ws  = (float*)d_ws;                  // NFT*B partials (1 MB)

    spline_fused<<<NFT * (B_SZ / RB), 512, 0, stream>>>(
        uw, uh, udl, udr, (const float4*)inputs, (float4*)out, ws);
    lad_reduce<<<B_SZ / 256, 256, 0, stream>>>(ws, lad);
}

// Round 4
// 85.471 us; speedup vs baseline: 1.1796x; 1.1796x over previous
//
#include <hip/hip_runtime.h>

#define B_SZ 4096
#define D_SZ 1024
#define NB 32
#define DF 16          // features per tile
#define RB 512         // rows per tile
#define NFT (D_SZ / DF)   // 64 feature tiles
#define LSQ_STRIDE 9   // shifted-edge quads: 9 float4 per feature
#define CO_STRIDE  33  // coef quads: 33 float4 per feature

constexpr float MBW = 0.001f;
constexpr float MBH = 0.001f;

// ---------------------------------------------------------------------------
// Round-0 proven structure (normal launch, lad memset, device atomicAdd) with
// two latency-oriented hardening edits:
//  1. __launch_bounds__(512, 4): cap VGPR at 128 -> guarantee 2 blocks/CU
//     (4 waves/SIMD) for latency hiding of the dependent LDS-search chains.
//  2. Coarse-boundary table as 28 NAMED scalars + compile-time-j macro (no
//     pointer-select over private arrays -> guaranteed registers, rule #20).
// Cooperative variants (rounds 2-3) are abandoned: grid.sync degrades under
// the harness's graph capture (lad-only corruption, out intact, twice).
// ---------------------------------------------------------------------------
__global__ __launch_bounds__(512, 4) void spline_fused(
    const float* __restrict__ uw, const float* __restrict__ uh,
    const float* __restrict__ udl, const float* __restrict__ udr,
    const float4* __restrict__ inp,
    float4* __restrict__ out, float* __restrict__ lad)
{
    __shared__ float4 sLsQ  [DF * LSQ_STRIDE];   // 2.3 KB
    __shared__ float4 sCoefQ[DF * CO_STRIDE];    // 8.45 KB

    const int tid = threadIdx.x;
    const int ft = blockIdx.x & 63;              // 64 feature tiles
    const int rt = blockIdx.x >> 6;              // 8 row tiles
    const int f0 = ft * DF;
    const int r0 = rt * RB;

    // ---------------- phase 1: params, one segment per feature ----------------
    {
        const int s = tid >> 5;        // feature within tile: 0..15
        const int k = tid & 31;        // bin
        const int f = f0 + s;

        const float w_raw = uw[f * NB + k];
        const float h_raw = uh[f * NB + k];

        float m = w_raw;
        for (int mm = 16; mm >= 1; mm >>= 1) m = fmaxf(m, __shfl_xor(m, mm));
        const float e = __expf(w_raw - m);
        float sum = e;
        for (int mm = 16; mm >= 1; mm >>= 1) sum += __shfl_xor(sum, mm);
        const float w = MBW + (1.0f - MBW * NB) * (e / sum);

        float mh = h_raw;
        for (int mm = 16; mm >= 1; mm >>= 1) mh = fmaxf(mh, __shfl_xor(mh, mm));
        const float eh = __expf(h_raw - mh);
        float sumh = eh;
        for (int mm = 16; mm >= 1; mm >>= 1) sumh += __shfl_xor(sumh, mm);
        const float h = MBH + (1.0f - MBH * NB) * (eh / sumh);

        const float slope = h / w;

        float cw = w, ch = h;
        for (int off = 1; off < 32; off <<= 1) {
            float t1 = __shfl_up(cw, off, 32);
            float t2 = __shfl_up(ch, off, 32);
            if (k >= off) { cw += t1; ch += t2; }
        }
        float chl = __shfl_up(ch, 1, 32); if (k == 0) chl = 0.0f;
        const float Ls = (k == 31) ? 2.0f : cw;   // sentinel > any x in [0,1)

        const float slope_n = __shfl_down(slope, 1, 32);
        const float w_n     = __shfl_down(w, 1, 32);
        const float min1 = fminf(fabsf(slope), fabsf(slope_n));
        const float min2 = 0.5f * (w_n * slope + w * slope_n) / (w + w_n);
        const float sg  = (slope   > 0.f ? 1.f : 0.f) - (slope   < 0.f ? 1.f : 0.f);
        const float sgn = (slope_n > 0.f ? 1.f : 0.f) - (slope_n < 0.f ? 1.f : 0.f);
        const float inner = fminf(min1, min2) * (sg + sgn);

        float d_right;
        if (k == 31) {
            const float x = udr[f];
            d_right = (1.0f / (1.0f + __expf(-x))) * 3.0f * slope;
        } else {
            d_right = inner;
        }
        const float inner_prev = __shfl_up(inner, 1, 32);
        float d_left;
        if (k == 0) {
            const float x = udl[f];
            d_left = (1.0f / (1.0f + __expf(-x))) * 3.0f * slope;
        } else {
            d_left = inner_prev;
        }

        const float a = (d_left + d_right - 2.0f * slope) / (w * w);
        const float b = (3.0f * slope - 2.0f * d_left - d_right) / w;

        sCoefQ[s * CO_STRIDE + k] = make_float4(a, b, d_left, chl);

        float q0 = __shfl(Ls, (4 * k - 1) & 31, 32);
        float q1 = __shfl(Ls, (4 * k    ) & 31, 32);
        float q2 = __shfl(Ls, (4 * k + 1) & 31, 32);
        float q3 = __shfl(Ls, (4 * k + 2) & 31, 32);
        if (k == 0) q0 = 0.0f;                    // L[-1]
        if (k < 8) sLsQ[s * LSQ_STRIDE + k] = make_float4(q0, q1, q2, q3);
    }
    __syncthreads();

    // ---------------- phase 2: evaluate ----------------
    const int lane   = tid & 63;
    const int waveId = tid >> 6;          // 0..7
    const int flq    = lane >> 4;         // feature quad: 0..3
    const int rl     = lane & 15;         // row within wave group
    const int flbase = flq * 4;

    // coarse quad boundaries as NAMED registers: Cj_c = L[4c+3] of feature
    // (flbase+j). No private arrays, no pointer selects -> guaranteed VGPRs.
#define LOAD_C(J, N0,N1,N2,N3,N4,N5,N6)                                     \
    const float N0 = sLsQ[(flbase + J) * LSQ_STRIDE + 1].x;                 \
    const float N1 = sLsQ[(flbase + J) * LSQ_STRIDE + 2].x;                 \
    const float N2 = sLsQ[(flbase + J) * LSQ_STRIDE + 3].x;                 \
    const float N3 = sLsQ[(flbase + J) * LSQ_STRIDE + 4].x;                 \
    const float N4 = sLsQ[(flbase + J) * LSQ_STRIDE + 5].x;                 \
    const float N5 = sLsQ[(flbase + J) * LSQ_STRIDE + 6].x;                 \
    const float N6 = sLsQ[(flbase + J) * LSQ_STRIDE + 7].x;

    LOAD_C(0, c0a, c0b, c0c, c0d, c0e, c0f, c0g)
    LOAD_C(1, c1a, c1b, c1c, c1d, c1e, c1f, c1g)
    LOAD_C(2, c2a, c2b, c2c, c2d, c2e, c2f, c2g)
    LOAD_C(3, c3a, c3b, c3c, c3d, c3e, c3g, c3h)
#undef LOAD_C

    const int rbase = r0 + waveId * 16 + rl;          // +128 per iter
    const int base  = rbase * (D_SZ / 4) + ft * 4 + flq;
    const int iterStride = 128 * (D_SZ / 4);          // 128 rows per iter

    // per-feature evaluation, J a compile-time literal, boundaries named regs
#define EVAL_J(J, X, OUTSLOT, N0,N1,N2,N3,N4,N5,N6)                         \
    {                                                                        \
        const float x = (X);                                                 \
        int o = (x >= N0 ? 1 : 0) + (x >= N1 ? 1 : 0) + (x >= N2 ? 1 : 0)    \
              + (x >= N3 ? 1 : 0) + (x >= N4 ? 1 : 0) + (x >= N5 ? 1 : 0)    \
              + (x >= N6 ? 1 : 0);                                           \
        const float4 q = sLsQ[(flbase + J) * LSQ_STRIDE + o];                \
        const int cnt = (x >= q.y ? 1 : 0) + (x >= q.z ? 1 : 0)              \
                      + (x >= q.w ? 1 : 0);                                  \
        const float cwl = (cnt == 0) ? q.x                                   \
                        : (cnt == 1) ? q.y                                   \
                        : (cnt == 2) ? q.z : q.w;                            \
        const float4 cf = sCoefQ[(flbase + J) * CO_STRIDE + 4 * o + cnt];    \
        const float s = x - cwl;                                             \
        float oo = ((cf.x * s + cf.y) * s + cf.z) * s + cf.w;                \
        OUTSLOT = fminf(fmaxf(oo, 0.0f), 1.0f);                              \
        const float der = (3.0f * cf.x * s + 2.0f * cf.y) * s + cf.z;        \
        prod *= der;                                                         \
    }

    #pragma unroll
    for (int it = 0; it < RB / 128; ++it) {
        const float4 x4 = inp[base + it * iterStride];

        float4 o4;
        float prod = 1.0f;

        EVAL_J(0, x4.x, o4.x, c0a, c0b, c0c, c0d, c0e, c0f, c0g)
        EVAL_J(1, x4.y, o4.y, c1a, c1b, c1c, c1d, c1e, c1f, c1g)
        EVAL_J(2, x4.z, o4.z, c2a, c2b, c2c, c2d, c2e, c2f, c2g)
        EVAL_J(3, x4.w, o4.w, c3a, c3b, c3c, c3d, c3e, c3g, c3h)

        out[base + it * iterStride] = o4;

        // sum across the 4 feature quads (xor classes share lane&15 == row)
        float lsum = __logf(fabsf(prod));
        lsum += __shfl_xor(lsum, 16);
        lsum += __shfl_xor(lsum, 32);
        // device-scope atomic RMW: coherent across XCDs (round-0 proven)
        if (lane < 16) atomicAdd(&lad[rbase + it * 128], lsum);
    }
#undef EVAL_J
}

// ---------------------------------------------------------------------------
extern "C" void kernel_launch(void* const* d_in, const int* in_sizes, int n_in,
                              void* d_out, int out_size, void* d_ws, size_t ws_size,
                              hipStream_t stream)
{
    const float* inputs = (const float*)d_in[0];
    const float* uw     = (const float*)d_in[1];
    const float* uh     = (const float*)d_in[2];
    const float* udl    = (const float*)d_in[3];
    const float* udr    = (const float*)d_in[4];

    float* out = (float*)d_out;                 // B*D outputs
    float* lad = out + (size_t)B_SZ * D_SZ;     // B logabsdet sums

    hipMemsetAsync(lad, 0, (size_t)B_SZ * sizeof(float), stream);
    spline_fused<<<NFT * (B_SZ / RB), 512, 0, stream>>>(
        uw, uh, udl, udr, (const float4*)inputs, (float4*)out, lad);
}

// Round 5
// 84.295 us; speedup vs baseline: 1.1960x; 1.0140x over previous
//
#include <hip/hip_runtime.h>

#define B_SZ 4096
#define D_SZ 1024
#define NB 32
#define DF 16          // features per tile
#define RB 512         // rows per tile
#define NFT (D_SZ / DF)   // 64 feature tiles
#define LSQ_STRIDE 9   // shifted-edge quads: 9 float4 per feature
#define CO_STRIDE  33  // coef quads: 33 float4 per feature

constexpr float MBW = 0.001f;
constexpr float MBH = 0.001f;

// ---------------------------------------------------------------------------
// Round-4 structure (normal launch, lad memset, device atomicAdd — proven),
// phase 2 restructured for memory-level parallelism:
//   - global x4 loads software-pipelined one iteration ahead (the ~900-cycle
//     HBM/L2 latency hides under the previous iteration's eval+store);
//   - per iteration, LDS traffic batched into TWO wide stages: 4 independent
//     edge-quad reads issued back-to-back, then 4 independent coef reads --
//     instead of 8 serialized read->wait->use chains (2 x ~120 cy exposed
//     per iter instead of 8 x ~120 cy).
// Math is bit-identical to round 0/4.
// ---------------------------------------------------------------------------
__global__ __launch_bounds__(512, 4) void spline_fused(
    const float* __restrict__ uw, const float* __restrict__ uh,
    const float* __restrict__ udl, const float* __restrict__ udr,
    const float4* __restrict__ inp,
    float4* __restrict__ out, float* __restrict__ lad)
{
    __shared__ float4 sLsQ  [DF * LSQ_STRIDE];   // 2.3 KB
    __shared__ float4 sCoefQ[DF * CO_STRIDE];    // 8.45 KB

    const int tid = threadIdx.x;
    const int ft = blockIdx.x & 63;              // 64 feature tiles
    const int rt = blockIdx.x >> 6;              // 8 row tiles
    const int f0 = ft * DF;
    const int r0 = rt * RB;

    // ---------------- phase 1: params, one segment per feature ----------------
    {
        const int s = tid >> 5;        // feature within tile: 0..15
        const int k = tid & 31;        // bin
        const int f = f0 + s;

        const float w_raw = uw[f * NB + k];
        const float h_raw = uh[f * NB + k];

        float m = w_raw;
        for (int mm = 16; mm >= 1; mm >>= 1) m = fmaxf(m, __shfl_xor(m, mm));
        const float e = __expf(w_raw - m);
        float sum = e;
        for (int mm = 16; mm >= 1; mm >>= 1) sum += __shfl_xor(sum, mm);
        const float w = MBW + (1.0f - MBW * NB) * (e / sum);

        float mh = h_raw;
        for (int mm = 16; mm >= 1; mm >>= 1) mh = fmaxf(mh, __shfl_xor(mh, mm));
        const float eh = __expf(h_raw - mh);
        float sumh = eh;
        for (int mm = 16; mm >= 1; mm >>= 1) sumh += __shfl_xor(sumh, mm);
        const float h = MBH + (1.0f - MBH * NB) * (eh / sumh);

        const float slope = h / w;

        float cw = w, ch = h;
        for (int off = 1; off < 32; off <<= 1) {
            float t1 = __shfl_up(cw, off, 32);
            float t2 = __shfl_up(ch, off, 32);
            if (k >= off) { cw += t1; ch += t2; }
        }
        float chl = __shfl_up(ch, 1, 32); if (k == 0) chl = 0.0f;
        const float Ls = (k == 31) ? 2.0f : cw;   // sentinel > any x in [0,1)

        const float slope_n = __shfl_down(slope, 1, 32);
        const float w_n     = __shfl_down(w, 1, 32);
        const float min1 = fminf(fabsf(slope), fabsf(slope_n));
        const float min2 = 0.5f * (w_n * slope + w * slope_n) / (w + w_n);
        const float sg  = (slope   > 0.f ? 1.f : 0.f) - (slope   < 0.f ? 1.f : 0.f);
        const float sgn = (slope_n > 0.f ? 1.f : 0.f) - (slope_n < 0.f ? 1.f : 0.f);
        const float inner = fminf(min1, min2) * (sg + sgn);

        float d_right;
        if (k == 31) {
            const float x = udr[f];
            d_right = (1.0f / (1.0f + __expf(-x))) * 3.0f * slope;
        } else {
            d_right = inner;
        }
        const float inner_prev = __shfl_up(inner, 1, 32);
        float d_left;
        if (k == 0) {
            const float x = udl[f];
            d_left = (1.0f / (1.0f + __expf(-x))) * 3.0f * slope;
        } else {
            d_left = inner_prev;
        }

        const float a = (d_left + d_right - 2.0f * slope) / (w * w);
        const float b = (3.0f * slope - 2.0f * d_left - d_right) / w;

        sCoefQ[s * CO_STRIDE + k] = make_float4(a, b, d_left, chl);

        float q0 = __shfl(Ls, (4 * k - 1) & 31, 32);
        float q1 = __shfl(Ls, (4 * k    ) & 31, 32);
        float q2 = __shfl(Ls, (4 * k + 1) & 31, 32);
        float q3 = __shfl(Ls, (4 * k + 2) & 31, 32);
        if (k == 0) q0 = 0.0f;                    // L[-1]
        if (k < 8) sLsQ[s * LSQ_STRIDE + k] = make_float4(q0, q1, q2, q3);
    }
    __syncthreads();

    // ---------------- phase 2: evaluate ----------------
    const int lane   = tid & 63;
    const int waveId = tid >> 6;          // 0..7
    const int flq    = lane >> 4;         // feature quad: 0..3
    const int rl     = lane & 15;         // row within wave group
    const int flbase = flq * 4;

    // coarse quad boundaries as NAMED registers: L[4c+3] of feature flbase+j
#define LOAD_C(J, N0,N1,N2,N3,N4,N5,N6)                                     \
    const float N0 = sLsQ[(flbase + J) * LSQ_STRIDE + 1].x;                 \
    const float N1 = sLsQ[(flbase + J) * LSQ_STRIDE + 2].x;                 \
    const float N2 = sLsQ[(flbase + J) * LSQ_STRIDE + 3].x;                 \
    const float N3 = sLsQ[(flbase + J) * LSQ_STRIDE + 4].x;                 \
    const float N4 = sLsQ[(flbase + J) * LSQ_STRIDE + 5].x;                 \
    const float N5 = sLsQ[(flbase + J) * LSQ_STRIDE + 6].x;                 \
    const float N6 = sLsQ[(flbase + J) * LSQ_STRIDE + 7].x;

    LOAD_C(0, c0a, c0b, c0c, c0d, c0e, c0f, c0g)
    LOAD_C(1, c1a, c1b, c1c, c1d, c1e, c1f, c1g)
    LOAD_C(2, c2a, c2b, c2c, c2d, c2e, c2f, c2g)
    LOAD_C(3, c3a, c3b, c3c, c3d, c3e, c3f, c3g)
#undef LOAD_C

    const int rbase = r0 + waveId * 16 + rl;          // +128 per iter
    const int base  = rbase * (D_SZ / 4) + ft * 4 + flq;
    const int iterStride = 128 * (D_SZ / 4);          // 128 rows per iter

    // 7 coarse compares -> quad index (independent cmps, single adder tree)
#define COARSE(X, N0,N1,N2,N3,N4,N5,N6)                                     \
    ( ((X) >= N0 ? 1 : 0) + ((X) >= N1 ? 1 : 0) + ((X) >= N2 ? 1 : 0)       \
    + ((X) >= N3 ? 1 : 0) + ((X) >= N4 ? 1 : 0) + ((X) >= N5 ? 1 : 0)       \
    + ((X) >= N6 ? 1 : 0) )

    float4 xc = inp[base];                            // iter-0 input

    #pragma unroll
    for (int it = 0; it < RB / 128; ++it) {
        // prefetch next iteration's input: HBM latency hides under this
        // iteration's eval + store + reduce tail
        float4 xn;
        if (it < RB / 128 - 1) xn = inp[base + (it + 1) * iterStride];

        const float x0 = xc.x, x1 = xc.y, x2 = xc.z, x3 = xc.w;

        // ---- stage 1: all coarse searches (pure VALU, no LDS) ----
        const int o0 = COARSE(x0, c0a, c0b, c0c, c0d, c0e, c0f, c0g);
        const int o1 = COARSE(x1, c1a, c1b, c1c, c1d, c1e, c1f, c1g);
        const int o2 = COARSE(x2, c2a, c2b, c2c, c2d, c2e, c2f, c2g);
        const int o3 = COARSE(x3, c3a, c3b, c3c, c3d, c3e, c3f, c3g);

        // ---- stage 2: 4 independent edge-quad reads, issued back-to-back ----
        const float4 q0 = sLsQ[(flbase + 0) * LSQ_STRIDE + o0];
        const float4 q1 = sLsQ[(flbase + 1) * LSQ_STRIDE + o1];
        const float4 q2 = sLsQ[(flbase + 2) * LSQ_STRIDE + o2];
        const float4 q3 = sLsQ[(flbase + 3) * LSQ_STRIDE + o3];

        // ---- stage 3: fine search (VALU only) ----
        const int cnt0 = (x0 >= q0.y) + (x0 >= q0.z) + (x0 >= q0.w);
        const int cnt1 = (x1 >= q1.y) + (x1 >= q1.z) + (x1 >= q1.w);
        const int cnt2 = (x2 >= q2.y) + (x2 >= q2.z) + (x2 >= q2.w);
        const int cnt3 = (x3 >= q3.y) + (x3 >= q3.z) + (x3 >= q3.w);
        const float cwl0 = (cnt0 == 0) ? q0.x : (cnt0 == 1) ? q0.y : (cnt0 == 2) ? q0.z : q0.w;
        const float cwl1 = (cnt1 == 0) ? q1.x : (cnt1 == 1) ? q1.y : (cnt1 == 2) ? q1.z : q1.w;
        const float cwl2 = (cnt2 == 0) ? q2.x : (cnt2 == 1) ? q2.y : (cnt2 == 2) ? q2.z : q2.w;
        const float cwl3 = (cnt3 == 0) ? q3.x : (cnt3 == 1) ? q3.y : (cnt3 == 2) ? q3.z : q3.w;

        // ---- stage 4: 4 independent coef reads, issued back-to-back ----
        const float4 cf0 = sCoefQ[(flbase + 0) * CO_STRIDE + 4 * o0 + cnt0];
        const float4 cf1 = sCoefQ[(flbase + 1) * CO_STRIDE + 4 * o1 + cnt1];
        const float4 cf2 = sCoefQ[(flbase + 2) * CO_STRIDE + 4 * o2 + cnt2];
        const float4 cf3 = sCoefQ[(flbase + 3) * CO_STRIDE + 4 * o3 + cnt3];

        // ---- stage 5: polynomials (pure VALU) ----
        const float s0 = x0 - cwl0, s1 = x1 - cwl1, s2 = x2 - cwl2, s3 = x3 - cwl3;
        float4 o4;
        o4.x = fminf(fmaxf(((cf0.x * s0 + cf0.y) * s0 + cf0.z) * s0 + cf0.w, 0.0f), 1.0f);
        o4.y = fminf(fmaxf(((cf1.x * s1 + cf1.y) * s1 + cf1.z) * s1 + cf1.w, 0.0f), 1.0f);
        o4.z = fminf(fmaxf(((cf2.x * s2 + cf2.y) * s2 + cf2.z) * s2 + cf2.w, 0.0f), 1.0f);
        o4.w = fminf(fmaxf(((cf3.x * s3 + cf3.y) * s3 + cf3.z) * s3 + cf3.w, 0.0f), 1.0f);

        const float der0 = (3.0f * cf0.x * s0 + 2.0f * cf0.y) * s0 + cf0.z;
        const float der1 = (3.0f * cf1.x * s1 + 2.0f * cf1.y) * s1 + cf1.z;
        const float der2 = (3.0f * cf2.x * s2 + 2.0f * cf2.y) * s2 + cf2.z;
        const float der3 = (3.0f * cf3.x * s3 + 2.0f * cf3.y) * s3 + cf3.z;
        const float prod = (der0 * der1) * (der2 * der3);

        out[base + it * iterStride] = o4;

        // sum across the 4 feature quads (xor classes share lane&15 == row)
        float lsum = __logf(fabsf(prod));
        lsum += __shfl_xor(lsum, 16);
        lsum += __shfl_xor(lsum, 32);
        // device-scope atomic RMW: coherent across XCDs (round-0 proven)
        if (lane < 16) atomicAdd(&lad[rbase + it * 128], lsum);

        xc = xn;
    }
#undef COARSE
}

// ---------------------------------------------------------------------------
extern "C" void kernel_launch(void* const* d_in, const int* in_sizes, int n_in,
                              void* d_out, int out_size, void* d_ws, size_t ws_size,
                              hipStream_t stream)
{
    const float* inputs = (const float*)d_in[0];
    const float* uw     = (const float*)d_in[1];
    const float* uh     = (const float*)d_in[2];
    const float* udl    = (const float*)d_in[3];
    const float* udr    = (const float*)d_in[4];

    float* out = (float*)d_out;                 // B*D outputs
    float* lad = out + (size_t)B_SZ * D_SZ;     // B logabsdet sums

    hipMemsetAsync(lad, 0, (size_t)B_SZ * sizeof(float), stream);
    spline_fused<<<NFT * (B_SZ / RB), 512, 0, stream>>>(
        uw, uh, udl, udr, (const float4*)inputs, (float4*)out, lad);
}